// Round 1
// baseline (471.137 us; speedup 1.0000x reference)
//
#include <hip/hip_runtime.h>

using f32x4  = __attribute__((ext_vector_type(4))) float;
using short8 = __attribute__((ext_vector_type(8))) short;
using short4v= __attribute__((ext_vector_type(4))) short;
typedef __attribute__((ext_vector_type(8))) __bf16 bf16x8;

__device__ static inline short f2bf(float f){
    unsigned u = __builtin_bit_cast(unsigned, f);
    u += 0x7fffu + ((u >> 16) & 1u);      // RNE
    return (short)(u >> 16);
}

__device__ static inline void gload_lds16(const void* g, void* l){
    __builtin_amdgcn_global_load_lds(
        (const __attribute__((address_space(1))) void*)g,
        (__attribute__((address_space(3))) void*)l, 16, 0, 0);
}

// ---------------- GEMM: C[M,N] = A[M,K] @ B[N,K]^T  (bf16 in, f32 acc) ----
// 128x128 tile, BK=64, 4 waves of 64x64, mfma_f32_16x16x32_bf16.
// LDS layout: [row][8 chunks of 16B], chunk stored at (kchunk ^ (row&7)).
// Staging pre-swizzles the GLOBAL source so global_load_lds' linear dest
// lands swizzled (rule #21); ds_read applies the same XOR -> 2-way conflicts.
#define BKK 64

template<int EPI>
__global__ __launch_bounds__(256, 2)
void gemm_bt(const short* __restrict__ A, const short* __restrict__ B,
             float* __restrict__ outF, short* __restrict__ outB,
             const float* __restrict__ bias,
             const float* __restrict__ addmat, const float* __restrict__ mask,
             int K, int ldc, int Ncheck,
             long sA, long sB, long sC, long sX, int maskStride)
{
    __shared__ short Abuf[128*BKK];
    __shared__ short Bbuf[128*BKK];
    const int tid  = threadIdx.x;
    const int wave = tid >> 6;
    const int lane = tid & 63;
    const int bz   = blockIdx.z;
    const int m0   = blockIdx.y * 128;
    const int n0   = blockIdx.x * 128;
    const short* Ab = A + (long)bz * sA;
    const short* Bb = B + (long)bz * sB;

    const int wr = (wave >> 1) * 64;   // wave row offset in tile
    const int wc = (wave &  1) * 64;   // wave col offset in tile

    f32x4 acc[4][4];
    #pragma unroll
    for (int i=0;i<4;++i)
        #pragma unroll
        for (int j=0;j<4;++j) acc[i][j] = (f32x4){0.f,0.f,0.f,0.f};

    // staging: wave covers rows [wave*32, wave*32+32), 4 issues x 8 rows
    const int srow = wave*32 + (lane >> 3);
    const int kch  = (lane & 7) ^ (lane >> 3);       // pre-swizzled source chunk
    const short* gA = Ab + (long)(m0 + srow)*K + kch*8;
    const short* gB = Bb + (long)(n0 + srow)*K + kch*8;
    short* lA = Abuf + wave*32*BKK;                   // wave-uniform LDS base
    short* lB = Bbuf + wave*32*BKK;

    for (int k0 = 0; k0 < K; k0 += BKK) {
        __syncthreads();
        #pragma unroll
        for (int is=0; is<4; ++is){
            gload_lds16(gA + k0 + (long)is*8*K, lA + is*8*BKK);
            gload_lds16(gB + k0 + (long)is*8*K, lB + is*8*BKK);
        }
        __syncthreads();
        #pragma unroll
        for (int ks=0; ks<2; ++ks){
            bf16x8 af[4], bfr[4];
            const int chunk = ks*4 + (lane >> 4);
            #pragma unroll
            for (int mi=0;mi<4;++mi){
                int row = wr + mi*16 + (lane & 15);
                af[mi] = *(const bf16x8*)((const char*)Abuf + row*128 + ((chunk ^ (row & 7))<<4));
            }
            #pragma unroll
            for (int ni=0;ni<4;++ni){
                int row = wc + ni*16 + (lane & 15);
                bfr[ni] = *(const bf16x8*)((const char*)Bbuf + row*128 + ((chunk ^ (row & 7))<<4));
            }
            #pragma unroll
            for (int mi=0;mi<4;++mi)
                #pragma unroll
                for (int ni=0;ni<4;++ni)
                    acc[mi][ni] = __builtin_amdgcn_mfma_f32_16x16x32_bf16(af[mi], bfr[ni], acc[mi][ni], 0, 0, 0);
        }
    }

    // epilogue: C/D layout col=lane&15, row=(lane>>4)*4+reg  [m89/m91]
    const int rb = (lane >> 4) * 4;
    const int cb = lane & 15;
    #pragma unroll
    for (int mi=0;mi<4;++mi){
        #pragma unroll
        for (int r=0;r<4;++r){
            const int row = m0 + wr + mi*16 + rb + r;
            #pragma unroll
            for (int ni=0;ni<4;++ni){
                const int col = n0 + wc + ni*16 + cb;
                float v = acc[mi][ni][r];
                if constexpr (EPI == 0) {           // scores: + src + mask*-1e4, f32 out
                    v += addmat[(long)bz*sX + (long)row*ldc + col]
                         - 10000.f * mask[bz*maskStride + col];
                    outF[(long)bz*sC + (long)row*ldc + col] = v;
                } else if constexpr (EPI == 1) {    // plain bf16 out
                    outB[(long)bz*sC + (long)row*ldc + col] = f2bf(v);
                } else if constexpr (EPI == 3) {    // f32 + bias, col-bounded
                    if (col < Ncheck) outF[(long)row*ldc + col] = v + bias[col];
                } else if constexpr (EPI == 4) {    // bf16 + bias
                    outB[(long)row*ldc + col] = f2bf(v + bias[col]);
                }
            }
        }
    }
}

// ---------------- f32 -> bf16 (vector, zero-pad tail [n, ntot)) -----------
__global__ __launch_bounds__(256)
void conv_bf16(const float* __restrict__ in, short* __restrict__ out, long n, long ntot)
{
    const long stride = (long)gridDim.x * 2048;
    for (long i = ((long)blockIdx.x*256 + threadIdx.x)*8; i < ntot; i += stride){
        short8 o = (short8){0,0,0,0,0,0,0,0};
        if (i < n){
            f32x4 a = *(const f32x4*)(in + i);
            f32x4 b = *(const f32x4*)(in + i + 4);
            o[0]=f2bf(a[0]); o[1]=f2bf(a[1]); o[2]=f2bf(a[2]); o[3]=f2bf(a[3]);
            o[4]=f2bf(b[0]); o[5]=f2bf(b[1]); o[6]=f2bf(b[2]); o[7]=f2bf(b[3]);
        }
        *(short8*)(out + i) = o;
    }
}

// ---------------- f32 [R,Cin] -> bf16 [R,Cpad], zero cols >= Cin ----------
__global__ __launch_bounds__(256)
void conv_pad(const float* __restrict__ in, short* __restrict__ out,
              int Cin, int Cpad, int total)
{
    int idx = blockIdx.x*256 + threadIdx.x;
    if (idx >= total) return;
    int r = idx / Cpad, c = idx - r*Cpad;
    short v = 0;
    if (c < Cin) v = f2bf(in[(long)r*Cin + c]);
    out[idx] = v;
}

// ---------------- per-batch transpose f32 [R,C] -> bf16 [C,R] -------------
__global__ __launch_bounds__(256)
void transpose_to_bf16(const float* __restrict__ in, short* __restrict__ out, int R, int C)
{
    __shared__ float t[32][33];
    const long boff = (long)blockIdx.z * R * C;
    const float* inb = in + boff;
    short* outb = out + boff;
    int c0 = blockIdx.x*32, r0 = blockIdx.y*32;
    int tx = threadIdx.x & 31, ty = threadIdx.x >> 5;   // 32 x 8
    #pragma unroll
    for (int j=0;j<32;j+=8) t[ty+j][tx] = inb[(long)(r0+ty+j)*C + c0+tx];
    __syncthreads();
    #pragma unroll
    for (int j=0;j<32;j+=8) outb[(long)(c0+ty+j)*R + r0+tx] = f2bf(t[tx][ty+j]);
}

// ---------------- wave-per-row softmax, f32 [.,512] -> bf16 ---------------
__global__ __launch_bounds__(256)
void softmax_bf16(const float* __restrict__ scores, short* __restrict__ alpha, int L)
{
    const int row  = blockIdx.x*4 + (threadIdx.x >> 6);
    const int lane = threadIdx.x & 63;
    const float* p = scores + (long)row*L + lane*8;
    f32x4 v0 = *(const f32x4*)p;
    f32x4 v1 = *(const f32x4*)(p+4);
    float x[8] = {v0[0],v0[1],v0[2],v0[3],v1[0],v1[1],v1[2],v1[3]};
    float m = x[0];
    #pragma unroll
    for (int j=1;j<8;++j) m = fmaxf(m, x[j]);
    #pragma unroll
    for (int off=32; off; off>>=1) m = fmaxf(m, __shfl_xor(m, off));
    float s = 0.f;
    #pragma unroll
    for (int j=0;j<8;++j){ x[j] = __expf(x[j]-m); s += x[j]; }
    #pragma unroll
    for (int off=32; off; off>>=1) s += __shfl_xor(s, off);
    const float rinv = 1.f / s;
    short8 o;
    #pragma unroll
    for (int j=0;j<8;++j) o[j] = f2bf(x[j]*rinv);
    *(short8*)(alpha + (long)row*L + lane*8) = o;
}

// ---------------- fused exact-gelu + LayerNorm, wave per row (H=768) ------
__global__ __launch_bounds__(256)
void gelu_ln(const float* __restrict__ lin, short* __restrict__ h,
             const float* __restrict__ g, const float* __restrict__ b, int H)
{
    const int row  = blockIdx.x*4 + (threadIdx.x >> 6);
    const int lane = threadIdx.x & 63;
    const float* p = lin + (long)row*H;
    float x[12];
    #pragma unroll
    for (int c=0;c<3;++c){
        f32x4 v = *(const f32x4*)(p + c*256 + lane*4);
        x[c*4+0]=v[0]; x[c*4+1]=v[1]; x[c*4+2]=v[2]; x[c*4+3]=v[3];
    }
    float sum=0.f, sq=0.f;
    #pragma unroll
    for (int j=0;j<12;++j){
        float t = 0.5f * x[j] * (1.f + erff(x[j]*0.70710678118654752f));
        x[j] = t; sum += t; sq += t*t;
    }
    #pragma unroll
    for (int off=32; off; off>>=1){ sum += __shfl_xor(sum, off); sq += __shfl_xor(sq, off); }
    const float mu  = sum * (1.f/768.f);
    const float var = sq  * (1.f/768.f) - mu*mu;
    const float inv = rsqrtf(var + 1e-12f);
    #pragma unroll
    for (int c=0;c<3;++c){
        short4v o;
        #pragma unroll
        for (int j=0;j<4;++j){
            int col = c*256 + lane*4 + j;
            o[j] = f2bf((x[c*4+j]-mu)*inv*g[col] + b[col]);
        }
        *(short4v*)(h + (long)row*H + c*256 + lane*4) = o;
    }
}

// --------------------------------------------------------------------------
extern "C" void kernel_launch(void* const* d_in, const int* in_sizes, int n_in,
                              void* d_out, int out_size, void* d_ws, size_t ws_size,
                              hipStream_t stream)
{
    const float* src_scores = (const float*)d_in[0];
    const float* seq_hidden = (const float*)d_in[1];
    const float* seq_mask   = (const float*)d_in[2];
    const float* pos_emb    = (const float*)d_in[3];
    const float* Wp         = (const float*)d_in[4];
    const float* bp         = (const float*)d_in[5];
    const float* Wt         = (const float*)d_in[6];
    const float* bt         = (const float*)d_in[7];
    const float* ln_g       = (const float*)d_in[8];
    const float* ln_b       = (const float*)d_in[9];
    const float* Wd         = (const float*)d_in[10];
    const float* dec_bias   = (const float*)d_in[11];
    float* out = (float*)d_out;

    const int B=8, L=512, H=768, V=30522, Vp=30592, Kp=256;

    // ws: only stage-6 inputs must survive until the final GEMM (53.3 MB)
    const size_t need = ((size_t)Vp*H + (size_t)B*L*H) * sizeof(short);
    if (ws_size < need) return;
    short* wd_bf = (short*)d_ws;               // [Vp, H] bf16, zero-padded rows
    short* h_bf  = wd_bf + (long)Vp*H;         // [B*L, H] bf16

    // everything else is dead before stage 6 -> stash in d_out (500 MB)
    char* sc = (char*)d_out;
    short* sh_nat = (short*)sc;  sc += (long)B*L*H*2;   // [b][s][h] bf16
    short* sh_t   = (short*)sc;  sc += (long)B*L*H*2;   // [b][h][s] bf16
    short* pe_p   = (short*)sc;  sc += (long)L*Kp*2;    // [512,256] bf16 (K-pad)
    short* wp_p   = (short*)sc;  sc += (long)H*Kp*2;    // [768,256] bf16
    short* pos_h  = (short*)sc;  sc += (long)L*H*2;     // [512,768] bf16
    short* wt_bf  = (short*)sc;  sc += (long)H*H*2;     // [768,768] bf16
    float* scoresb= (float*)sc;  sc += (long)B*L*L*4;   // [8,512,512] f32
    short* alpha  = (short*)sc;  sc += (long)B*L*L*2;   // [8,512,512] bf16
    short* seqsum = (short*)sc;  sc += (long)B*L*H*2;   // [8,512,768] bf16
    float* lin5   = (float*)sc;  sc += (long)B*L*H*4;   // [4096,768] f32

    // --- conversions ---
    {   long n=(long)V*H, ntot=(long)Vp*H;
        int blocks=(int)((ntot+2047)/2048); if (blocks>2048) blocks=2048;
        conv_bf16<<<dim3(blocks),256,0,stream>>>(Wd, wd_bf, n, ntot); }
    {   long n=(long)H*H; int blocks=(int)((n+2047)/2048);
        conv_bf16<<<dim3(blocks),256,0,stream>>>(Wt, wt_bf, n, n); }
    {   long n=(long)B*L*H; int blocks=(int)((n+2047)/2048); if (blocks>2048) blocks=2048;
        conv_bf16<<<dim3(blocks),256,0,stream>>>(seq_hidden, sh_nat, n, n); }
    transpose_to_bf16<<<dim3(H/32, L/32, B),256,0,stream>>>(seq_hidden, sh_t, L, H);
    {   int total=L*Kp;
        conv_pad<<<dim3((total+255)/256),256,0,stream>>>(pos_emb, pe_p, 200, Kp, total); }
    {   int total=H*Kp;
        conv_pad<<<dim3((total+255)/256),256,0,stream>>>(Wp, wp_p, 200, Kp, total); }

    // --- stage1: pos_h = pos_emb @ Wp^T + bp  -> bf16 [512,768]
    gemm_bt<4><<<dim3(H/128, L/128, 1),256,0,stream>>>(
        pe_p, wp_p, nullptr, pos_h, bp, nullptr, nullptr,
        Kp, H, H, 0L, 0L, 0L, 0L, 0);

    // --- stage2: scores[b,l,s] = pos_h[l].sh[b,s] + src + mask*-1e4 (f32)
    gemm_bt<0><<<dim3(L/128, L/128, B),256,0,stream>>>(
        pos_h, sh_nat, scoresb, nullptr, nullptr, src_scores, seq_mask,
        H, L, L, 0L, (long)L*H, (long)L*L, (long)L*L, L);

    // --- stage3: softmax rows of 512 -> alpha bf16
    softmax_bf16<<<dim3(B*L/4),256,0,stream>>>(scoresb, alpha, L);

    // --- stage4: seqsum[b,l,h] = alpha[b,l,:] @ sh[b,:,h]  (B^T = sh_t)
    gemm_bt<1><<<dim3(H/128, L/128, B),256,0,stream>>>(
        alpha, sh_t, nullptr, seqsum, nullptr, nullptr, nullptr,
        L, H, H, (long)L*L, (long)H*L, (long)L*H, 0L, 0);

    // --- stage5: lin5 = seqsum @ Wt^T + bt (f32)
    gemm_bt<3><<<dim3(H/128, (B*L)/128, 1),256,0,stream>>>(
        seqsum, wt_bf, lin5, nullptr, bt, nullptr, nullptr,
        H, H, H, 0L, 0L, 0L, 0L, 0);

    // --- gelu(exact) + LayerNorm -> h bf16
    gelu_ln<<<dim3(B*L/4),256,0,stream>>>(lin5, h_bf, ln_g, ln_b, H);

    // --- stage6: out = h @ Wd^T + dec_bias  [4096, 30522] f32
    gemm_bt<3><<<dim3(Vp/128, (B*L)/128, 1),256,0,stream>>>(
        h_bf, wd_bf, out, nullptr, dec_bias, nullptr, nullptr,
        H, V, V, 0L, 0L, 0L, 0L, 0);
}